// Round 15
// baseline (777.104 us; speedup 1.0000x reference)
//
#include <hip/hip_runtime.h>

// LSTM B=512 T=1024 H=150 I=1 + Linear(150->1) + sigmoid.
// ROUND-15: r14 (700us: 256 blocks x 2 seqs, merge-5 PW, setprio) + VALU trim:
//  - bias rides the MFMA C-operand: bias_acc[5] per-lane f32x4 (D row=4q+r =>
//    gate=r) -> no per-step acc zero-init, no k=150 column.
//  - x_t folded into PW: g[r] += alpha*W_ih[orow]*x_t with per-lane consts,
//    x_t via one ds_read_u16 per wave -> no k=151 column, no x staging/writes.
//  - waves 6,7 skip their padded 5th tile (10 fewer MFMA/block).
// Step accounting (r14 measured): matrix 800 cyc/SIMD (floor), VALU 600,
//   LDS 480, overlap to 1641. This round targets the VALU term.
// M = 608 real vrows (4*cell+gate), 38 tiles; vrow 600 (tile37 row8) = W_out.
// K = 160: k<150 = h (LDS dbuf), k>=150 = zero pad.
// Weights pre-scaled by -log2e / +2log2e: PW = 5 exp2 + 2 rcp per cell.

typedef _Float16 half8 __attribute__((ext_vector_type(8)));
typedef float f32x4 __attribute__((ext_vector_type(4)));

#define LOG2E 1.44269504088896340736f
#define TWOLOG2E 2.88539008177792681472f

__global__
__attribute__((amdgpu_flat_work_group_size(512, 512), amdgpu_waves_per_eu(2, 2)))
void lstm_kernel(
    const float* __restrict__ x,      // [512][1024]
    const float* __restrict__ W_ih,   // [600]
    const float* __restrict__ W_hh,   // [600][150]
    const float* __restrict__ b_ih,   // [600]
    const float* __restrict__ b_hh,   // [600]
    const float* __restrict__ W_out,  // [150]
    const float* __restrict__ b_out,  // [1]
    float* __restrict__ out)          // [512][1024]
{
  const int tid  = threadIdx.x;
  const int wid  = tid >> 6;
  const int lane = tid & 63;
  const int q    = lane >> 4;   // k-subchunk for A/B frags; D row group
  const int b    = lane & 15;   // D col; A-frag row m
  const int br   = b & 1;       // real batch (cols duplicate mod 2)
  const int bid  = blockIdx.x;

  __shared__ __align__(16) _Float16 hbuf[2][2][168];
  __shared__ _Float16 xlds[2][1032];

  // ---- prologue: zero hbuf (cols 150+ stay zero forever), stage x ----
  for (int i = tid; i < 2*2*168; i += 512)
    (&hbuf[0][0][0])[i] = (_Float16)0.0f;
  {
    const float4* x4 = (const float4*)(x + (size_t)bid * 2 * 1024);
    const int row = tid >> 8, c4 = tid & 255;
    float4 v = x4[row*256 + c4];
    xlds[row][c4*4+0] = (_Float16)v.x;
    xlds[row][c4*4+1] = (_Float16)v.y;
    xlds[row][c4*4+2] = (_Float16)v.z;
    xlds[row][c4*4+3] = (_Float16)v.w;
  }
  __syncthreads();

  // ---- tile ownership: wave w -> {w + 8j, j<NT}; NT = 5 (w<6) else 4 ----
  const int NT = (wid < 6) ? 5 : 4;
  const float bo = b_out[0];

  // ---- weight fragments: 5 tiles x 5 chunks = 100 VGPR (h columns only) ----
  half8 wf[5][5];
#pragma unroll
  for (int j = 0; j < 5; ++j) {
#pragma unroll
    for (int s = 0; s < 5; ++s) wf[j][s] = (half8)(_Float16)0.0f;
    if (j < NT) {
      const int tg   = wid + 8*j;
      const int vrow = tg*16 + b;          // A-frag: m = lane&15
      const int cell = vrow >> 2, gate = vrow & 3;
      const float alpha = (gate == 2) ? TWOLOG2E : -LOG2E;
#pragma unroll
      for (int s = 0; s < 5; ++s) {
        half8 v;
#pragma unroll
        for (int jj = 0; jj < 8; ++jj) {
          const int k = s*32 + q*8 + jj;   // same (q,j)->k map as B frags
          float w = 0.0f;
          if (k < 150) {
            if (vrow == 600)      w = -LOG2E * W_out[k];
            else if (cell < 150)  w = alpha * W_hh[(gate*150 + cell)*150 + k];
          }
          v[jj] = (_Float16)w;
        }
        wf[j][s] = v;
      }
    }
  }

  // ---- bias C-init: bias_acc[j][r] for D row 4q+r (gate = r) ----
  f32x4 bias_acc[5];
#pragma unroll
  for (int j = 0; j < 5; ++j) {
#pragma unroll
    for (int r = 0; r < 4; ++r) {
      const int vrow = (wid + 8*j)*16 + 4*q + r;
      const int cell = vrow >> 2;
      float v = 0.0f;
      if (j < NT) {
        if (vrow == 600)      v = -LOG2E * bo;
        else if (cell < 150) {
          const float alpha = (r == 2) ? TWOLOG2E : -LOG2E;
          v = alpha * (b_ih[r*150 + cell] + b_hh[r*150 + cell]);
        }
      }
      bias_acc[j][r] = v;
    }
  }

  // ---- merged-PW constants: lane e=b>>1 owns cell 4*(wid+8e)+q ----
  const int  e    = b >> 1;
  const int  cellm = 4*(wid + 8*e) + q;
  const bool wen  = (e < NT) && (cellm < 150);
  const int  wc   = wen ? cellm : 152;     // clamp; pointer unused if !wen
  f32x4 wih_c;
#pragma unroll
  for (int r = 0; r < 4; ++r) {
    float v = 0.0f;
    if (wen) {
      const float alpha = (r == 2) ? TWOLOG2E : -LOG2E;
      v = alpha * W_ih[r*150 + cellm];
    }
    wih_c[r] = v;
  }

  float cst = 0.f;                 // one cell per lane
  const bool is_out = (wid == 5) && (q == 2) && (b < 2);  // vrow600: tile37,reg0
  float* outp = out + ((size_t)bid*2 + br) * 1024;

  const _Float16* rb0 = &hbuf[0][br][q*8];
  const _Float16* rb1 = &hbuf[1][br][q*8];
  _Float16* wp0 = &hbuf[0][br][wc];
  _Float16* wp1 = &hbuf[1][br][wc];
  const _Float16* xp = &xlds[br][0];

  for (int t = 0; t <= 1024; ++t) {
    const _Float16* r0 = (t & 1) ? rb1 : rb0;
    f32x4 acc[5];

    __builtin_amdgcn_s_setprio(1);
    {
      const half8 bf0 = *(const half8*)(r0);
#pragma unroll
      for (int j = 0; j < 4; ++j)
        acc[j] = __builtin_amdgcn_mfma_f32_16x16x32_f16(wf[j][0], bf0, bias_acc[j], 0,0,0);
      if (wid < 6)
        acc[4] = __builtin_amdgcn_mfma_f32_16x16x32_f16(wf[4][0], bf0, bias_acc[4], 0,0,0);
      else
        acc[4] = bias_acc[4];
    }
#pragma unroll
    for (int s = 1; s < 5; ++s) {
      const half8 bfs = *(const half8*)(r0 + s*32);
#pragma unroll
      for (int j = 0; j < 4; ++j)
        acc[j] = __builtin_amdgcn_mfma_f32_16x16x32_f16(wf[j][s], bfs, acc[j], 0,0,0);
      if (wid < 6)
        acc[4] = __builtin_amdgcn_mfma_f32_16x16x32_f16(wf[4][s], bfs, acc[4], 0,0,0);
    }
    __builtin_amdgcn_s_setprio(0);

    // out_{t-1} = sigmoid(Wout.h_{t-1} + b_out); tile 37 slot 4, reg 0
    if (is_out && t >= 1)
      outp[t-1] = __builtin_amdgcn_rcpf(1.0f + __builtin_amdgcn_exp2f(acc[4][0]));
    if (t == 1024) break;

    // ---- merged PW: lane e selects its tile's gates (16 cndmask) ----
    const float xf = (float)xp[t];   // x_t for this lane's batch (2-addr bcast)
    f32x4 g;
#pragma unroll
    for (int r = 0; r < 4; ++r) {
      const float t01 = (b & 2) ? acc[1][r] : acc[0][r];
      const float t23 = (b & 2) ? acc[3][r] : acc[2][r];
      const float t03 = (b & 4) ? t23 : t01;
      const float sel = (b & 8) ? acc[4][r] : t03;   // e>=5 -> junk (guarded)
      g[r] = fmaf(wih_c[r], xf, sel);
    }
    // g: 0=i',1=f',2=g',3=o' (pre-scaled preacts)
    const float ei = __builtin_amdgcn_exp2f(g[0]);
    const float ef = __builtin_amdgcn_exp2f(g[1]);
    const float eg = __builtin_amdgcn_exp2f(g[2]);
    const float eo = __builtin_amdgcn_exp2f(g[3]);
    const float A   = 1.0f + ei;     // 1/i
    const float F   = 1.0f + ef;     // 1/f
    const float G1  = eg + 1.0f;
    const float Gm  = eg - 1.0f;     // g = Gm/G1
    const float AG  = A * G1;
    const float num = fmaf(cst, AG, Gm * F);
    const float cn  = num * __builtin_amdgcn_rcpf(F * AG);
    cst = cn;
    const float ec = __builtin_amdgcn_exp2f(TWOLOG2E * cn);
    const float hv = (ec - 1.0f) *
                     __builtin_amdgcn_rcpf((1.0f + eo) * (ec + 1.0f)); // o*tanh(c)
    if (wen) {                       // h(t) -> buf[(t+1)&1]
      _Float16* w = (t & 1) ? wp0 : wp1;
      *w = (_Float16)hv;
    }
    __syncthreads();
  }
}

extern "C" void kernel_launch(void* const* d_in, const int* in_sizes, int n_in,
                              void* d_out, int out_size, void* d_ws, size_t ws_size,
                              hipStream_t stream) {
  const float* x     = (const float*)d_in[0];
  const float* W_ih  = (const float*)d_in[1];
  const float* W_hh  = (const float*)d_in[2];
  const float* b_ih  = (const float*)d_in[3];
  const float* b_hh  = (const float*)d_in[4];
  const float* W_out = (const float*)d_in[5];
  const float* b_out = (const float*)d_in[6];
  lstm_kernel<<<dim3(256), dim3(512), 0, stream>>>(
      x, W_ih, W_hh, b_ih, b_hh, W_out, b_out, (float*)d_out);
}

// Round 16
// 616.551 us; speedup vs baseline: 1.2604x; 1.2604x over previous
//
#include <hip/hip_runtime.h>

// LSTM B=512 T=1024 H=150 I=1 + Linear(150->1) + sigmoid.
// ROUND-16: r14 base (700us) + HYBRID MX-fp8 matrix.
//   r14 counters: MfmaUtil 47% + VALUBusy 37% ~= whole step -> matrix issue
//   (970 cyc/SIMD = 50 x 19.4) is the floor and doesn't overlap VALU.
//   Replace K-chunks s0-s3 (k=0..127, pure W_hh*h) of each tile with ONE
//   mfma_scale_f32_16x16x128_f8f6f4 (fp8 e4m3 A/B, all scales=2^0 via 0x7F
//   bytes -> scale-byte-layout-proof); keep chunk s4 (cells 128-149 + bias
//   k=150 + x k=151) in f16 exactly as r14. Matrix: 5 instr/tile -> 2
//   (34.5 + 19.4 cyc/SIMD), per-SIMD 970 -> ~540. LDS reads 5 -> 3 b128.
//   Layout safety: A,B share the same (lane,reg)->k map so k-permutation
//   cancels; uniform scales permutation-invariant; C/D shape-determined.
//   h cells 0-127 stored to fp8 panel via manual branchless e4m3 encode.
// Numerics: only W_hh[:,0:128]*h in fp8 (x/bias/tail f16). Risk: absmax
//   0.0039 -> est 0.005-0.009 vs threshold 0.0104.
// Structure kept from r14: 256 blocks x 2 seqs, 8 waves, merge-5 PW (lane
//   e=b>>1 selects gates via 16 cndmask), setprio around MFMA, waves 6/7
//   own 4 tiles (unpadded: their slot-4 MFMAs skipped, acc[4]=0).

typedef _Float16 half8 __attribute__((ext_vector_type(8)));
typedef int int32x8 __attribute__((ext_vector_type(8)));
typedef float f32x4 __attribute__((ext_vector_type(4)));

#define LOG2E 1.44269504088896340736f
#define TWOLOG2E 2.88539008177792681472f

// branchless f32 -> fp8 e4m3 (RNE-ish round-half-up; |v| < 448 assumed)
__device__ inline unsigned enc_fp8(float v) {
  const float a = fabsf(v);
  const unsigned s = (__float_as_uint(v) >> 24) & 0x80u;
  const unsigned bits = __float_as_uint(a) + 0x80000u;       // round mantissa
  const unsigned code_n = (bits >> 20) - (120u << 3);        // (E-120)<<3 | m3
  const unsigned code_d = (unsigned)(a * 512.0f + 0.5f);     // denormal 2^-9
  const unsigned code = (a < 0.015625f) ? code_d : code_n;   // 2^-6 boundary
  return s | (code & 0x7Fu);
}

__global__
__attribute__((amdgpu_flat_work_group_size(512, 512), amdgpu_waves_per_eu(2, 2)))
void lstm_kernel(
    const float* __restrict__ x,      // [512][1024]
    const float* __restrict__ W_ih,   // [600]
    const float* __restrict__ W_hh,   // [600][150]
    const float* __restrict__ b_ih,   // [600]
    const float* __restrict__ b_hh,   // [600]
    const float* __restrict__ W_out,  // [150]
    const float* __restrict__ b_out,  // [1]
    float* __restrict__ out)          // [512][1024]
{
  const int tid  = threadIdx.x;
  const int wid  = tid >> 6;
  const int lane = tid & 63;
  const int q    = lane >> 4;   // k-subchunk selector; D row group
  const int b    = lane & 15;   // D col; A-frag row m
  const int br   = b & 1;       // real batch (cols duplicate mod 2)
  const int bid  = blockIdx.x;

  __shared__ __align__(16) _Float16 hbuf[2][2][168];            // f16: k=128..159
  __shared__ __align__(64) unsigned char h8[2][2][128];          // fp8: k=0..127
  __shared__ _Float16 xlds[2][1032];

  // ---- prologue: zero panels, stage x ----
  for (int i = tid; i < 2*2*168; i += 512)
    (&hbuf[0][0][0])[i] = (_Float16)0.0f;
  if (tid < 128) ((unsigned*)&h8[0][0][0])[tid] = 0u;
  {
    const float4* x4 = (const float4*)(x + (size_t)bid * 2 * 1024);
    const int row = tid >> 8, c4 = tid & 255;
    float4 v = x4[row*256 + c4];
    xlds[row][c4*4+0] = (_Float16)v.x;
    xlds[row][c4*4+1] = (_Float16)v.y;
    xlds[row][c4*4+2] = (_Float16)v.z;
    xlds[row][c4*4+3] = (_Float16)v.w;
  }
  __syncthreads();
  if (tid < 4) hbuf[tid>>1][tid&1][150] = (_Float16)1.0f;  // bias col, both bufs
  if (tid < 2) hbuf[0][tid][151] = xlds[tid][0];           // x_0
  __syncthreads();

  // ---- tile ownership: wave w -> {w + 8j, j<NT}; NT = 5 (w<6) else 4 ----
  const int NT = (wid < 6) ? 5 : 4;
  const float bo = b_out[0];

  // ---- A fragments ----
  // fp8 (k=0..127): wf8[j] = 8 dwords, byte (d,c) = k = q*32 + 4d + c
  int32x8 wf8[5];
  // f16 tail (k=128..159): wf16[j][jj]: k = 128 + q*8 + jj
  half8 wf16[5];
#pragma unroll
  for (int j = 0; j < 5; ++j) {
#pragma unroll
    for (int d = 0; d < 8; ++d) wf8[j][d] = 0;
    wf16[j] = (half8)(_Float16)0.0f;
    if (j < NT) {
      const int vrow = (wid + 8*j)*16 + b;   // A-frag: m = lane&15
      const int cell = vrow >> 2, gate = vrow & 3;
      const float alpha = (gate == 2) ? TWOLOG2E : -LOG2E;
#pragma unroll
      for (int d = 0; d < 8; ++d) {
        unsigned dw = 0;
#pragma unroll
        for (int c = 0; c < 4; ++c) {
          const int k = q*32 + 4*d + c;      // 0..127, always a valid W col
          float w = 0.0f;
          if (vrow == 600)      w = -LOG2E * W_out[k];
          else if (cell < 150)  w = alpha * W_hh[(gate*150 + cell)*150 + k];
          dw |= enc_fp8(w) << (8*c);
        }
        wf8[j][d] = (int)dw;
      }
      half8 v;
#pragma unroll
      for (int jj = 0; jj < 8; ++jj) {
        const int k = 128 + q*8 + jj;        // 128..159
        float w = 0.0f;
        if (vrow == 600) {
          if (k < 150)       w = -LOG2E * W_out[k];
          else if (k == 150) w = -LOG2E * bo;
        } else if (cell < 150) {
          const int orow = gate*150 + cell;
          if (k < 150)       w = alpha * W_hh[orow*150 + k];
          else if (k == 150) w = alpha * (b_ih[orow] + b_hh[orow]);
          else if (k == 151) w = alpha * W_ih[orow];
        }
        v[jj] = (_Float16)w;
      }
      wf16[j] = v;
    }
  }

  float cst = 0.f;                 // one cell per lane
  const int  e     = b >> 1;       // merged-tile selector (0..7; >=5 junk)
  const int  cellm = 4*(wid + 8*e) + q;
  const bool wen   = (e < NT) && (cellm < 150);
  const bool w8    = wen && (cellm < 128);   // fp8-panel writer
  const bool w16   = wen && (cellm >= 128);  // f16-panel writer
  const int  wc8   = (cellm < 128) ? cellm : 0;
  const int  wc16  = (cellm >= 128 && cellm < 150) ? cellm : 152;
  const bool is_x  = (wid == 7) && (q == 0) && (b < 2);
  const bool is_out= (wid == 5) && (q == 2) && (b < 2);  // vrow600: tile37,reg0
  float* outp = out + ((size_t)bid*2 + br) * 1024;

  const unsigned char* p8r0 = &h8[0][br][q*32];
  const unsigned char* p8r1 = &h8[1][br][q*32];
  const _Float16* p16r0 = &hbuf[0][br][128 + q*8];
  const _Float16* p16r1 = &hbuf[1][br][128 + q*8];
  unsigned char* w8p0 = &h8[0][br][wc8];
  unsigned char* w8p1 = &h8[1][br][wc8];
  _Float16* w16p0 = &hbuf[0][br][wc16];
  _Float16* w16p1 = &hbuf[1][br][wc16];
  _Float16* xw0 = &hbuf[0][br][151];
  _Float16* xw1 = &hbuf[1][br][151];
  const f32x4 ZERO = {0.f, 0.f, 0.f, 0.f};

  for (int t = 0; t <= 1024; ++t) {
    _Float16 xv = (_Float16)0.0f;
    if (is_x && t < 1023) xv = xlds[b][t+1];   // issued early, used post-PW

    const int32x8 bf8 = *(const int32x8*)((t & 1) ? p8r1 : p8r0);
    const half8  bf16 = *(const half8*)((t & 1) ? p16r1 : p16r0);

    f32x4 acc[5];
    __builtin_amdgcn_s_setprio(1);
#pragma unroll
    for (int j = 0; j < 4; ++j) {
      acc[j] = __builtin_amdgcn_mfma_scale_f32_16x16x128_f8f6f4(
                   wf8[j], bf8, ZERO, 0, 0, 0, 0x7F7F7F7F, 0, 0x7F7F7F7F);
      acc[j] = __builtin_amdgcn_mfma_f32_16x16x32_f16(wf16[j], bf16, acc[j], 0,0,0);
    }
    if (wid < 6) {
      acc[4] = __builtin_amdgcn_mfma_scale_f32_16x16x128_f8f6f4(
                   wf8[4], bf8, ZERO, 0, 0, 0, 0x7F7F7F7F, 0, 0x7F7F7F7F);
      acc[4] = __builtin_amdgcn_mfma_f32_16x16x32_f16(wf16[4], bf16, acc[4], 0,0,0);
    } else {
      acc[4] = ZERO;
    }
    __builtin_amdgcn_s_setprio(0);

    // out_{t-1} = sigmoid(Wout.h_{t-1} + b_out); tile 37 slot 4, reg 0
    if (is_out && t >= 1)
      outp[t-1] = __builtin_amdgcn_rcpf(1.0f + __builtin_amdgcn_exp2f(acc[4][0]));
    if (t == 1024) break;

    // ---- merged PW: lane e selects its tile's gates (16 cndmask) ----
    f32x4 g;
#pragma unroll
    for (int r = 0; r < 4; ++r) {
      const float t01 = (b & 2) ? acc[1][r] : acc[0][r];
      const float t23 = (b & 2) ? acc[3][r] : acc[2][r];
      const float t03 = (b & 4) ? t23 : t01;
      g[r] = (b & 8) ? acc[4][r] : t03;   // e>=5 -> junk (guarded by wen)
    }
    // g: 0=i',1=f',2=g',3=o' (pre-scaled preacts)
    const float ei = __builtin_amdgcn_exp2f(g[0]);
    const float ef = __builtin_amdgcn_exp2f(g[1]);
    const float eg = __builtin_amdgcn_exp2f(g[2]);
    const float eo = __builtin_amdgcn_exp2f(g[3]);
    const float A   = 1.0f + ei;     // 1/i
    const float F   = 1.0f + ef;     // 1/f
    const float G1  = eg + 1.0f;
    const float Gm  = eg - 1.0f;     // g = Gm/G1
    const float AG  = A * G1;
    const float num = fmaf(cst, AG, Gm * F);
    const float cn  = num * __builtin_amdgcn_rcpf(F * AG);
    cst = cn;
    const float ec = __builtin_amdgcn_exp2f(TWOLOG2E * cn);
    const float hv = (ec - 1.0f) *
                     __builtin_amdgcn_rcpf((1.0f + eo) * (ec + 1.0f)); // o*tanh(c)
    // h(t) -> buf[(t+1)&1]: fp8 panel for cells<128, f16 panel for 128-149
    if (w8) {
      unsigned char* w = (t & 1) ? w8p0 : w8p1;
      *w = (unsigned char)enc_fp8(hv);
    }
    if (w16) {
      _Float16* w = (t & 1) ? w16p0 : w16p1;
      *w = (_Float16)hv;
    }
    if (is_x && t < 1023) {          // x_{t+1} -> same buffer
      _Float16* xw = (t & 1) ? xw0 : xw1;
      *xw = xv;
    }
    __syncthreads();
  }
}

extern "C" void kernel_launch(void* const* d_in, const int* in_sizes, int n_in,
                              void* d_out, int out_size, void* d_ws, size_t ws_size,
                              hipStream_t stream) {
  const float* x     = (const float*)d_in[0];
  const float* W_ih  = (const float*)d_in[1];
  const float* W_hh  = (const float*)d_in[2];
  const float* b_ih  = (const float*)d_in[3];
  const float* b_hh  = (const float*)d_in[4];
  const float* W_out = (const float*)d_in[5];
  const float* b_out = (const float*)d_in[6];
  lstm_kernel<<<dim3(256), dim3(512), 0, stream>>>(
      x, W_ih, W_hh, b_ih, b_hh, W_out, b_out, (float*)d_out);
}

// Round 17
// 539.341 us; speedup vs baseline: 1.4408x; 1.1432x over previous
//
#include <hip/hip_runtime.h>

// LSTM B=512 T=1024 H=150 I=1 + Linear(150->1) + sigmoid.
// ROUND-17: r16 base (617us: 256 blocks x 2 seqs, hybrid MX-fp8 K=128 +
//   f16 K=32 tail, merge-5 PW, setprio) + VALU/issue trim:
//   - unroll x4: static buffer parity (no (t&1) pointer cndmasks), all LDS
//     pointers literal per body (rule-#20 safe).
//   - out buffered in 4 named regs (static rotation o3,o0,o1,o2), ONE
//     aligned float4 store per 4 steps issued right after a barrier ->
//     per-barrier vmcnt drain sees no pending store; fixes the 14 MB
//     WRITE_SIZE anomaly from per-step 4-B stores.
//   - fp8 encode via v_cvt_pk_fp8_f32 builtin (1 instr vs ~10 manual),
//     __has_builtin-guarded.
// r16 counters: matrix 496 cyc/SIMD (MfmaUtil 30.8%), VALU 765 (47.5%) ->
//   VALU is the wall; this round removes ~150-200 cyc of per-step issue.
// M = 608 vrows (4*cell+gate), 38 tiles; vrow 600 (tile37 row8) = W_out.
// K: k<128 fp8 e4m3 MX (scales=2^0=0x7F); k=128..159 f16 (bias k150, x k151).
// Weights pre-scaled by -log2e / +2log2e: PW = 5 exp2 + 2 rcp per cell.

typedef _Float16 half8 __attribute__((ext_vector_type(8)));
typedef int int32x8 __attribute__((ext_vector_type(8)));
typedef float f32x4 __attribute__((ext_vector_type(4)));

#define LOG2E 1.44269504088896340736f
#define TWOLOG2E 2.88539008177792681472f

// branchless f32 -> fp8 e4m3 (fallback; |v| < 448)
__device__ inline unsigned enc_fp8_manual(float v) {
  const float a = fabsf(v);
  const unsigned s = (__float_as_uint(v) >> 24) & 0x80u;
  const unsigned bits = __float_as_uint(a) + 0x80000u;
  const unsigned code_n = (bits >> 20) - (120u << 3);
  const unsigned code_d = (unsigned)(a * 512.0f + 0.5f);
  const unsigned code = (a < 0.015625f) ? code_d : code_n;
  return s | (code & 0x7Fu);
}

__device__ inline unsigned char enc8(float v) {
#if __has_builtin(__builtin_amdgcn_cvt_pk_fp8_f32)
  return (unsigned char)(__builtin_amdgcn_cvt_pk_fp8_f32(v, v, 0, false) & 0xFF);
#else
  return (unsigned char)enc_fp8_manual(v);
#endif
}

__global__
__attribute__((amdgpu_flat_work_group_size(512, 512), amdgpu_waves_per_eu(2, 2)))
void lstm_kernel(
    const float* __restrict__ x,      // [512][1024]
    const float* __restrict__ W_ih,   // [600]
    const float* __restrict__ W_hh,   // [600][150]
    const float* __restrict__ b_ih,   // [600]
    const float* __restrict__ b_hh,   // [600]
    const float* __restrict__ W_out,  // [150]
    const float* __restrict__ b_out,  // [1]
    float* __restrict__ out)          // [512][1024]
{
  const int tid  = threadIdx.x;
  const int wid  = tid >> 6;
  const int lane = tid & 63;
  const int q    = lane >> 4;   // k-subchunk selector; D row group
  const int b    = lane & 15;   // D col; A-frag row m
  const int br   = b & 1;       // real batch (cols duplicate mod 2)
  const int bid  = blockIdx.x;

  __shared__ __align__(16) _Float16 hbuf[2][2][168];            // f16: k=128..159
  __shared__ __align__(64) unsigned char h8[2][2][128];          // fp8: k=0..127
  __shared__ _Float16 xlds[2][1032];

  // ---- prologue: zero panels, stage x ----
  for (int i = tid; i < 2*2*168; i += 512)
    (&hbuf[0][0][0])[i] = (_Float16)0.0f;
  if (tid < 128) ((unsigned*)&h8[0][0][0])[tid] = 0u;
  {
    const float4* x4 = (const float4*)(x + (size_t)bid * 2 * 1024);
    const int row = tid >> 8, c4 = tid & 255;
    float4 v = x4[row*256 + c4];
    xlds[row][c4*4+0] = (_Float16)v.x;
    xlds[row][c4*4+1] = (_Float16)v.y;
    xlds[row][c4*4+2] = (_Float16)v.z;
    xlds[row][c4*4+3] = (_Float16)v.w;
  }
  __syncthreads();
  if (tid < 4) hbuf[tid>>1][tid&1][150] = (_Float16)1.0f;  // bias col, both bufs
  if (tid < 2) hbuf[0][tid][151] = xlds[tid][0];           // x_0
  __syncthreads();

  // ---- tile ownership: wave w -> {w + 8j, j<NT}; NT = 5 (w<6) else 4 ----
  const int NT = (wid < 6) ? 5 : 4;
  const float bo = b_out[0];

  // ---- A fragments: fp8 (k<128) + f16 tail (k=128..159) ----
  int32x8 wf8[5];
  half8 wf16[5];
#pragma unroll
  for (int j = 0; j < 5; ++j) {
#pragma unroll
    for (int d = 0; d < 8; ++d) wf8[j][d] = 0;
    wf16[j] = (half8)(_Float16)0.0f;
    if (j < NT) {
      const int vrow = (wid + 8*j)*16 + b;   // A-frag: m = lane&15
      const int cell = vrow >> 2, gate = vrow & 3;
      const float alpha = (gate == 2) ? TWOLOG2E : -LOG2E;
#pragma unroll
      for (int d = 0; d < 8; ++d) {
        unsigned dw = 0;
#pragma unroll
        for (int c = 0; c < 4; ++c) {
          const int k = q*32 + 4*d + c;      // 0..127
          float w = 0.0f;
          if (vrow == 600)      w = -LOG2E * W_out[k];
          else if (cell < 150)  w = alpha * W_hh[(gate*150 + cell)*150 + k];
          dw |= enc_fp8_manual(w) << (8*c);
        }
        wf8[j][d] = (int)dw;
      }
      half8 v;
#pragma unroll
      for (int jj = 0; jj < 8; ++jj) {
        const int k = 128 + q*8 + jj;        // 128..159
        float w = 0.0f;
        if (vrow == 600) {
          if (k < 150)       w = -LOG2E * W_out[k];
          else if (k == 150) w = -LOG2E * bo;
        } else if (cell < 150) {
          const int orow = gate*150 + cell;
          if (k < 150)       w = alpha * W_hh[orow*150 + k];
          else if (k == 150) w = alpha * (b_ih[orow] + b_hh[orow]);
          else if (k == 151) w = alpha * W_ih[orow];
        }
        v[jj] = (_Float16)w;
      }
      wf16[j] = v;
    }
  }

  float cst = 0.f;                 // one cell per lane
  const int  e     = b >> 1;       // merged-tile selector (0..7; >=5 junk)
  const int  cellm = 4*(wid + 8*e) + q;
  const bool wen   = (e < NT) && (cellm < 150);
  const bool w8    = wen && (cellm < 128);   // fp8-panel writer
  const bool w16   = wen && (cellm >= 128);  // f16-panel writer
  const int  wc8   = (cellm < 128) ? cellm : 0;
  const int  wc16  = (cellm >= 128 && cellm < 150) ? cellm : 152;
  const bool is_x  = (wid == 7) && (q == 0) && (b < 2);
  const bool is_out= (wid == 5) && (q == 2) && (b < 2);  // vrow600: tile37,reg0
  float* outp = out + ((size_t)bid*2 + br) * 1024;

  const unsigned char* p8r0 = &h8[0][br][q*32];
  const unsigned char* p8r1 = &h8[1][br][q*32];
  const _Float16* p16r0 = &hbuf[0][br][128 + q*8];
  const _Float16* p16r1 = &hbuf[1][br][128 + q*8];
  unsigned char* w8p0 = &h8[0][br][wc8];
  unsigned char* w8p1 = &h8[1][br][wc8];
  _Float16* w16p0 = &hbuf[0][br][wc16];
  _Float16* w16p1 = &hbuf[1][br][wc16];
  _Float16* xw0 = &hbuf[0][br][151];
  _Float16* xw1 = &hbuf[1][br][151];
  const _Float16* xq = &xlds[b & 1][0];   // valid row for active is_x lanes
  const f32x4 ZERO = {0.f, 0.f, 0.f, 0.f};

  float o0 = 0.f, o1 = 0.f, o2 = 0.f, o3 = 0.f;  // out[4g-4..4g-1] ring

// One timestep U with compile-time parity PAR (buffers are literal).
// OREG <- out[U-1] on is_out lanes (OGATE guards the U==0 corner).
#define STEP_BODY(U, PAR, OREG, OGATE)                                        \
  {                                                                           \
    _Float16 xv = (_Float16)0.0f;                                             \
    if (is_x && (U) < 1023) xv = xq[(U) + 1];                                 \
    const int32x8 bf8 = *(const int32x8*)((PAR) ? p8r1 : p8r0);               \
    const half8 bf16  = *(const half8*)((PAR) ? p16r1 : p16r0);               \
    f32x4 acc[5];                                                             \
    __builtin_amdgcn_s_setprio(1);                                            \
    _Pragma("unroll")                                                         \
    for (int j = 0; j < 4; ++j) {                                             \
      acc[j] = __builtin_amdgcn_mfma_scale_f32_16x16x128_f8f6f4(              \
                   wf8[j], bf8, ZERO, 0, 0, 0, 0x7F7F7F7F, 0, 0x7F7F7F7F);    \
      acc[j] = __builtin_amdgcn_mfma_f32_16x16x32_f16(wf16[j], bf16,          \
                                                      acc[j], 0, 0, 0);       \
    }                                                                         \
    if (wid < 6) {                                                            \
      acc[4] = __builtin_amdgcn_mfma_scale_f32_16x16x128_f8f6f4(              \
                   wf8[4], bf8, ZERO, 0, 0, 0, 0x7F7F7F7F, 0, 0x7F7F7F7F);    \
      acc[4] = __builtin_amdgcn_mfma_f32_16x16x32_f16(wf16[4], bf16,          \
                                                      acc[4], 0, 0, 0);       \
    } else {                                                                  \
      acc[4] = ZERO;                                                          \
    }                                                                         \
    __builtin_amdgcn_s_setprio(0);                                            \
    if (is_out && (OGATE))                                                    \
      OREG = __builtin_amdgcn_rcpf(1.0f + __builtin_amdgcn_exp2f(acc[4][0])); \
    /* merged PW: lane e=b>>1 selects its tile's gates */                     \
    f32x4 g;                                                                  \
    _Pragma("unroll")                                                         \
    for (int r = 0; r < 4; ++r) {                                             \
      const float t01 = (b & 2) ? acc[1][r] : acc[0][r];                      \
      const float t23 = (b & 2) ? acc[3][r] : acc[2][r];                      \
      const float t03 = (b & 4) ? t23 : t01;                                  \
      g[r] = (b & 8) ? acc[4][r] : t03;                                       \
    }                                                                         \
    const float ei = __builtin_amdgcn_exp2f(g[0]);                            \
    const float ef = __builtin_amdgcn_exp2f(g[1]);                            \
    const float eg = __builtin_amdgcn_exp2f(g[2]);                            \
    const float eo = __builtin_amdgcn_exp2f(g[3]);                            \
    const float A   = 1.0f + ei;                                              \
    const float F   = 1.0f + ef;                                              \
    const float G1  = eg + 1.0f;                                              \
    const float Gm  = eg - 1.0f;                                              \
    const float AG  = A * G1;                                                 \
    const float num = fmaf(cst, AG, Gm * F);                                  \
    const float cn  = num * __builtin_amdgcn_rcpf(F * AG);                    \
    cst = cn;                                                                 \
    const float ec = __builtin_amdgcn_exp2f(TWOLOG2E * cn);                   \
    const float hv = (ec - 1.0f) *                                            \
                     __builtin_amdgcn_rcpf((1.0f + eo) * (ec + 1.0f));        \
    if (w8)  *((PAR) ? w8p0 : w8p1) = enc8(hv);                               \
    if (w16) *((PAR) ? w16p0 : w16p1) = (_Float16)hv;                         \
    if (is_x && (U) < 1023) *((PAR) ? xw0 : xw1) = xv;                        \
    __syncthreads();                                                          \
  }

  for (int t = 0; t < 1024; t += 4) {
    STEP_BODY(t + 0, 0, o3, t > 0)
    // out[t-4..t-1] as one aligned float4, issued right after the barrier
    if (is_out && t >= 4)
      *(float4*)(outp + t - 4) = (float4){o0, o1, o2, o3};
    STEP_BODY(t + 1, 1, o0, 1)
    STEP_BODY(t + 2, 0, o1, 1)
    STEP_BODY(t + 3, 1, o2, 1)
  }

  // ---- tail: step 1024 (parity 0): out[1023] then final quad ----
  if (wid == 5) {
    const int32x8 bf8 = *(const int32x8*)p8r0;
    const half8 bf16  = *(const half8*)p16r0;
    f32x4 a = __builtin_amdgcn_mfma_scale_f32_16x16x128_f8f6f4(
                  wf8[4], bf8, ZERO, 0, 0, 0, 0x7F7F7F7F, 0, 0x7F7F7F7F);
    a = __builtin_amdgcn_mfma_f32_16x16x32_f16(wf16[4], bf16, a, 0, 0, 0);
    if (is_out) {
      o3 = __builtin_amdgcn_rcpf(1.0f + __builtin_amdgcn_exp2f(a[0]));
      *(float4*)(outp + 1020) = (float4){o0, o1, o2, o3};
    }
  }
}

extern "C" void kernel_launch(void* const* d_in, const int* in_sizes, int n_in,
                              void* d_out, int out_size, void* d_ws, size_t ws_size,
                              hipStream_t stream) {
  const float* x     = (const float*)d_in[0];
  const float* W_ih  = (const float*)d_in[1];
  const float* W_hh  = (const float*)d_in[2];
  const float* b_ih  = (const float*)d_in[3];
  const float* b_hh  = (const float*)d_in[4];
  const float* W_out = (const float*)d_in[5];
  const float* b_out = (const float*)d_in[6];
  lstm_kernel<<<dim3(256), dim3(512), 0, stream>>>(
      x, W_ih, W_hh, b_ih, b_hh, W_out, b_out, (float*)d_out);
}